// Round 5
// baseline (154.645 us; speedup 1.0000x reference)
//
#include <hip/hip_runtime.h>
#include <hip/hip_bf16.h>

// Problem dims (fixed by the reference)
#define N_DIM 32
#define C_DIM 64
#define T_DIM 512
#define V_DIM 25
#define H_DIM 3
#define TT 4                              // t-values per block in pass 1
#define NBLK (N_DIM * (T_DIM / TT))       // 4096 blocks in pass 1
#define NTV (N_DIM * T_DIM * V_DIM)       // 409600 elements per channel
#define NTOT (N_DIM * C_DIM * T_DIM * V_DIM)
#define XPITCH 76                         // shorts per tu-row (152 B)
#define XROWS 108                         // 100 data rows + 8 zero-pad (u<32 spill)
#define VP 28                             // padded v-pitch of bf16 scratch
#define BN_EPS 1e-5f

typedef float f32x4 __attribute__((ext_vector_type(4)));
typedef short bf16x8 __attribute__((ext_vector_type(8)));
typedef short s16x4 __attribute__((ext_vector_type(4)));

__device__ __forceinline__ short f2bf(float f) {
    __hip_bfloat16 h = __float2bfloat16(f);   // RNE; pairs fuse to v_cvt_pk_bf16_f32
    return __builtin_bit_cast(short, h);
}

__device__ __forceinline__ bf16x8 ld_bf8(const short* p) {   // two b64 LDS reads
    s16x4 a = *(const s16x4*)p;
    s16x4 b = *(const s16x4*)(p + 4);
    bf16x8 r;
    r[0] = a[0]; r[1] = a[1]; r[2] = a[2]; r[3] = a[3];
    r[4] = b[0]; r[5] = b[1]; r[6] = b[2]; r[7] = b[3];
    return r;
}

// ---------------------------------------------------------------------------
// Pass 1 (register-fused MFMA):
//   out_pre[n,o,t,v] = sum_{h,c,u} W[h,o,c] A[h,v,u] x[n,c,t,u]
// GEMM1 per (t,uh): D1[u'][o] = mfma(A=x-frag rows u', B=W-frag cols o), K=c=64.
//   A-frag row m reads u(m) = (m>>2)*8 + uh*4 + (m&3), so lane (l15,hi) ends up
//   holding y[u = hi*8 + uh*4 + j][o = l15] — exactly GEMM2's B-fragment. y
//   never touches LDS.
// GEMM2 per t: acc[v][o] += mfma(A = A_h rows v, B = y-frag), K=u pad 32.
//   (af is zero for u>=25 / v>=25, nullifying pad-row garbage; pad rows zeroed
//    so 0*NaN can't occur.)
// TT=4 + #pragma unroll 2: two independent MFMA chains in flight per wave,
// LDS ~16 KB for higher residency — latency-hiding is the round-5 lever.
// SCR=1: bf16 scratch [n][o][t][VP] in d_ws, vector short4 stores.
// SCR=0: fp32 scratch = d_out in final layout, scalar stores (fallback).
// bias dropped: per-channel constant cancels exactly through BatchNorm.
// ---------------------------------------------------------------------------
template <int SCR>
__global__ __launch_bounds__(256) void gcn_pass1(
    const float* __restrict__ x, const float* __restrict__ A,
    const float* __restrict__ W, void* __restrict__ scratch_,
    float* __restrict__ partial)
{
    __shared__ __align__(16) short x_sT[XROWS * XPITCH];   // 16,416 B

    const int blk  = blockIdx.x;
    const int n    = blk >> 7;             // 128 t-groups per n
    const int t0   = (blk & 127) * TT;
    const int tid  = threadIdx.x;
    const int lane = tid & 63;
    const int w    = tid >> 6;             // wave 0..3 -> o in [16w, 16w+16)
    const int l15  = lane & 15;
    const int hi   = lane >> 4;

    // ---- W fragments: lane: o = 16w + l15, k(c) = s*32 + hi*8 + i
    bf16x8 wf[H_DIM][2];
    #pragma unroll
    for (int h = 0; h < H_DIM; ++h)
        #pragma unroll
        for (int s = 0; s < 2; ++s) {
            const f32x4* wp = (const f32x4*)(W + h * 4096 + (16 * w + l15) * 64
                                             + s * 32 + hi * 8);
            f32x4 lo = wp[0], hv = wp[1];
            bf16x8 f;
            #pragma unroll
            for (int i = 0; i < 4; ++i) { f[i] = f2bf(lo[i]); f[4 + i] = f2bf(hv[i]); }
            wf[h][s] = f;
        }

    // ---- A fragments: lane: v = vt*16 + l15, k(u) = hi*8 + i; zero pads
    bf16x8 af[H_DIM][2];
    #pragma unroll
    for (int h = 0; h < H_DIM; ++h)
        #pragma unroll
        for (int vt = 0; vt < 2; ++vt) {
            int v = vt * 16 + l15;
            bf16x8 f;
            #pragma unroll
            for (int i = 0; i < 8; ++i) {
                int u = hi * 8 + i;
                f[i] = (v < 25 && u < 25) ? f2bf(A[h * 625 + v * 25 + u]) : (short)0;
            }
            af[h][vt] = f;
        }

    // ---- stage x transposed: x_sT[tu][c], b64 writes, 4 coalesced load streams
    const float* xn = x + (size_t)n * (C_DIM * T_DIM * V_DIM) + t0 * 25;
    for (int e = tid; e < 1600; e += 256) {
        int cg = e / 100, tu = e - cg * 100;
        float f0 = xn[(4 * cg + 0) * 12800 + tu];
        float f1 = xn[(4 * cg + 1) * 12800 + tu];
        float f2 = xn[(4 * cg + 2) * 12800 + tu];
        float f3 = xn[(4 * cg + 3) * 12800 + tu];
        s16x4 p; p[0] = f2bf(f0); p[1] = f2bf(f1); p[2] = f2bf(f2); p[3] = f2bf(f3);
        *(s16x4*)&x_sT[tu * XPITCH + 4 * cg] = p;
    }
    // zero pad rows 100..107 (avoid stale-LDS NaN patterns reaching MFMA)
    for (int e = tid; e < 304; e += 256)
        ((int*)&x_sT[100 * XPITCH])[e] = 0;
    __syncthreads();

    // per-lane x-row base for the u-permutation: u = (l15>>2)*8 + uh*4 + (l15&3)
    const int ubase = ((l15 >> 2) * 8) + (l15 & 3);

    float s_tot = 0.f, q_tot = 0.f;
    const int o_glob = 16 * w + l15;

    #pragma unroll 2
    for (int t = 0; t < TT; ++t) {
        const short* xr0 = &x_sT[(t * 25 + ubase + 0) * XPITCH + hi * 8];  // uh=0
        const short* xr1 = &x_sT[(t * 25 + ubase + 4) * XPITCH + hi * 8];  // uh=1
        const bf16x8 xf00 = ld_bf8(xr0), xf01 = ld_bf8(xr0 + 32);
        const bf16x8 xf10 = ld_bf8(xr1), xf11 = ld_bf8(xr1 + 32);

        f32x4 acc2[2] = {f32x4{0.f, 0.f, 0.f, 0.f}, f32x4{0.f, 0.f, 0.f, 0.f}};

        #pragma unroll
        for (int h = 0; h < H_DIM; ++h) {
            f32x4 y0 = {0.f, 0.f, 0.f, 0.f}, y1 = {0.f, 0.f, 0.f, 0.f};
            y0 = __builtin_amdgcn_mfma_f32_16x16x32_bf16(xf00, wf[h][0], y0, 0, 0, 0);
            y0 = __builtin_amdgcn_mfma_f32_16x16x32_bf16(xf01, wf[h][1], y0, 0, 0, 0);
            y1 = __builtin_amdgcn_mfma_f32_16x16x32_bf16(xf10, wf[h][0], y1, 0, 0, 0);
            y1 = __builtin_amdgcn_mfma_f32_16x16x32_bf16(xf11, wf[h][1], y1, 0, 0, 0);
            bf16x8 yf;
            #pragma unroll
            for (int j = 0; j < 4; ++j) yf[j] = f2bf(y0[j]);
            #pragma unroll
            for (int j = 0; j < 4; ++j) yf[4 + j] = f2bf(y1[j]);
            acc2[0] = __builtin_amdgcn_mfma_f32_16x16x32_bf16(af[h][0], yf, acc2[0], 0, 0, 0);
            acc2[1] = __builtin_amdgcn_mfma_f32_16x16x32_bf16(af[h][1], yf, acc2[1], 0, 0, 0);
        }

        if (SCR) {
            // bf16 scratch [n][o][t][VP]: short4 stores, 8B-aligned
            short* sp = (short*)scratch_
                      + ((size_t)(n * 64 + o_glob) * 512 + (t0 + t)) * VP;
            s16x4 p0; p0[0] = f2bf(acc2[0][0]); p0[1] = f2bf(acc2[0][1]);
                      p0[2] = f2bf(acc2[0][2]); p0[3] = f2bf(acc2[0][3]);
            *(s16x4*)(sp + hi * 4) = p0;               // v = hi*4 .. hi*4+3
            if (hi < 2) {
                s16x4 p1; p1[0] = f2bf(acc2[1][0]); p1[1] = f2bf(acc2[1][1]);
                          p1[2] = f2bf(acc2[1][2]); p1[3] = f2bf(acc2[1][3]);
                *(s16x4*)(sp + 16 + hi * 4) = p1;      // v = 16+hi*4 ..
            } else if (hi == 2) {
                sp[24] = f2bf(acc2[1][0]);             // v = 24
            }
        } else {
            float* op = (float*)scratch_
                      + ((size_t)(n * 64 + o_glob) * 512 + (t0 + t)) * 25;
            #pragma unroll
            for (int j = 0; j < 4; ++j) op[hi * 4 + j] = acc2[0][j];
            if (hi < 2) {
                #pragma unroll
                for (int j = 0; j < 4; ++j) op[16 + hi * 4 + j] = acc2[1][j];
            } else if (hi == 2) {
                op[24] = acc2[1][0];
            }
        }

        // ---- per-lane stats accumulate (shuffle hoisted out of loop)
        float s = acc2[0][0] + acc2[0][1] + acc2[0][2] + acc2[0][3];
        float q = fmaf(acc2[0][0], acc2[0][0], fmaf(acc2[0][1], acc2[0][1],
                  fmaf(acc2[0][2], acc2[0][2], acc2[0][3] * acc2[0][3])));
        if (hi < 2) {
            #pragma unroll
            for (int j = 0; j < 4; ++j) {
                float v1 = acc2[1][j]; s += v1; q = fmaf(v1, v1, q);
            }
        } else if (hi == 2) {
            float v1 = acc2[1][0]; s += v1; q = fmaf(v1, v1, q);
        }
        s_tot += s; q_tot += q;
    }

    s_tot += __shfl_xor(s_tot, 16); q_tot += __shfl_xor(q_tot, 16);
    s_tot += __shfl_xor(s_tot, 32); q_tot += __shfl_xor(q_tot, 32);
    if (hi == 0) {
        partial[blk * 128 + o_glob]      = s_tot;
        partial[blk * 128 + 64 + o_glob] = q_tot;
    }
}

// ---------------------------------------------------------------------------
// Pass 2: reduce partials -> per-channel mean and rsqrt(var+eps)
// ---------------------------------------------------------------------------
__global__ __launch_bounds__(256) void gcn_stats(
    const float* __restrict__ partial, float* __restrict__ stats)
{
    const int o = blockIdx.x;      // 64 blocks, one per channel
    const int tid = threadIdx.x;
    float s = 0.f, q = 0.f;
    for (int blk = tid; blk < NBLK; blk += 256) {
        s += partial[blk * 128 + o];
        q += partial[blk * 128 + 64 + o];
    }
    __shared__ float rs[256], rq[256];
    rs[tid] = s; rq[tid] = q;
    __syncthreads();
    for (int off = 128; off > 0; off >>= 1) {
        if (tid < off) { rs[tid] += rs[tid + off]; rq[tid] += rq[tid + off]; }
        __syncthreads();
    }
    if (tid == 0) {
        float mean = rs[0] / (float)NTV;
        float var  = rq[0] / (float)NTV - mean * mean;   // biased, like jnp.var
        stats[o]      = mean;
        stats[64 + o] = rsqrtf(var + BN_EPS);
    }
}

// ---------------------------------------------------------------------------
// Pass 3 (bf16-scratch): out = relu(gamma*(pre-mean)*rsig + beta + x), float4
// ---------------------------------------------------------------------------
__global__ __launch_bounds__(256) void gcn_finalize_b(
    const float* __restrict__ x, const float* __restrict__ gamma,
    const float* __restrict__ beta, const float* __restrict__ stats,
    const unsigned short* __restrict__ scr, float* __restrict__ out)
{
    const int total4 = NTOT / 4;
    for (int i = blockIdx.x * blockDim.x + threadIdx.x; i < total4;
         i += gridDim.x * blockDim.x) {
        int e0 = i * 4;
        unsigned r = (unsigned)(((unsigned long long)e0 * 0x51EB851Full) >> 35); // /25
        int v0 = e0 - (int)r * 25;
        float4 xv = ((const float4*)x)[i];
        float res[4];
        #pragma unroll
        for (int k = 0; k < 4; ++k) {
            unsigned rr = r; int vv = v0 + k;
            if (vv >= 25) { rr = r + 1; vv -= 25; }    // at most one carry
            int chan = (rr >> 9) & 63;
            float pv = __uint_as_float((unsigned)scr[(size_t)rr * VP + vv] << 16);
            float m = stats[chan], rs = stats[64 + chan];
            float g = gamma[chan] * rs;
            float bc = beta[chan] - g * m;
            float xk = (&xv.x)[k];
            res[k] = fmaxf(fmaf(g, pv, bc) + xk, 0.f);
        }
        float4 o4; o4.x = res[0]; o4.y = res[1]; o4.z = res[2]; o4.w = res[3];
        ((float4*)out)[i] = o4;
    }
}

// ---------------------------------------------------------------------------
// Pass 3 (fallback, fp32 scratch == out): in-place elementwise
// ---------------------------------------------------------------------------
__global__ __launch_bounds__(256) void gcn_finalize_f(
    const float* __restrict__ x, const float* __restrict__ gamma,
    const float* __restrict__ beta, const float* __restrict__ stats,
    float* __restrict__ out)
{
    const int total4 = NTOT / 4;
    for (int i = blockIdx.x * blockDim.x + threadIdx.x; i < total4;
         i += gridDim.x * blockDim.x) {
        int chan = ((i * 4) / (T_DIM * V_DIM)) & 63;
        float4 p  = ((const float4*)out)[i];
        float4 xv = ((const float4*)x)[i];
        float m = stats[chan], r = stats[64 + chan];
        float g = gamma[chan] * r;
        float bc = beta[chan] - g * m;
        p.x = fmaxf(fmaf(g, p.x, bc) + xv.x, 0.f);
        p.y = fmaxf(fmaf(g, p.y, bc) + xv.y, 0.f);
        p.z = fmaxf(fmaf(g, p.z, bc) + xv.z, 0.f);
        p.w = fmaxf(fmaf(g, p.w, bc) + xv.w, 0.f);
        ((float4*)out)[i] = p;
    }
}

extern "C" void kernel_launch(void* const* d_in, const int* in_sizes, int n_in,
                              void* d_out, int out_size, void* d_ws, size_t ws_size,
                              hipStream_t stream) {
    const float* x     = (const float*)d_in[0];
    const float* A     = (const float*)d_in[1];
    const float* W     = (const float*)d_in[2];
    // d_in[3] = b : unused — per-channel bias cancels exactly through BatchNorm
    const float* gamma = (const float*)d_in[4];
    const float* beta  = (const float*)d_in[5];
    float* out = (float*)d_out;

    const size_t scr_bytes  = (size_t)N_DIM * C_DIM * T_DIM * VP * 2;   // 58.7 MB
    const size_t part_bytes = (size_t)(NBLK * 128 + 128) * 4;           // 2.0 MB

    if (ws_size >= scr_bytes + part_bytes) {
        unsigned short* scr = (unsigned short*)d_ws;
        float* partial = (float*)((char*)d_ws + scr_bytes);
        float* stats   = partial + NBLK * 128;
        gcn_pass1<1><<<NBLK, 256, 0, stream>>>(x, A, W, (void*)scr, partial);
        gcn_stats<<<64, 256, 0, stream>>>(partial, stats);
        gcn_finalize_b<<<2048, 256, 0, stream>>>(x, gamma, beta, stats, scr, out);
    } else {
        float* partial = (float*)d_ws;
        float* stats   = partial + NBLK * 128;
        gcn_pass1<0><<<NBLK, 256, 0, stream>>>(x, A, W, (void*)out, partial);
        gcn_stats<<<64, 256, 0, stream>>>(partial, stats);
        gcn_finalize_f<<<2048, 256, 0, stream>>>(x, gamma, beta, stats, out);
    }
}

// Round 6
// 138.502 us; speedup vs baseline: 1.1166x; 1.1166x over previous
//
#include <hip/hip_runtime.h>
#include <hip/hip_bf16.h>

// Problem dims (fixed by the reference)
#define N_DIM 32
#define C_DIM 64
#define T_DIM 512
#define V_DIM 25
#define H_DIM 3
#define TT 8                              // t-values per block in pass 1
#define NBLK (N_DIM * (T_DIM / TT))       // 2048 blocks in pass 1
#define NTV (N_DIM * T_DIM * V_DIM)       // 409600 elements per channel
#define NTOT (N_DIM * C_DIM * T_DIM * V_DIM)
#define XPITCH 76                         // shorts per tu-row (152 B)
#define XROWS 208                         // 200 data rows + 8 zero-pad
#define TILE_SH 1792                      // shorts per (blk,t) scratch tile (3584 B)
#define BN_EPS 1e-5f

typedef float f32x4 __attribute__((ext_vector_type(4)));
typedef short bf16x8 __attribute__((ext_vector_type(8)));
typedef short s16x4 __attribute__((ext_vector_type(4)));

__device__ __forceinline__ short f2bf(float f) {
    __hip_bfloat16 h = __float2bfloat16(f);   // RNE; pairs fuse to v_cvt_pk_bf16_f32
    return __builtin_bit_cast(short, h);
}
__device__ __forceinline__ float bf2f(short s) {
    return __uint_as_float(((unsigned)(unsigned short)s) << 16);
}

__device__ __forceinline__ bf16x8 ld_bf8(const short* p) {   // two b64 LDS reads
    s16x4 a = *(const s16x4*)p;
    s16x4 b = *(const s16x4*)(p + 4);
    bf16x8 r;
    r[0] = a[0]; r[1] = a[1]; r[2] = a[2]; r[3] = a[3];
    r[4] = b[0]; r[5] = b[1]; r[6] = b[2]; r[7] = b[3];
    return r;
}

// ---------------------------------------------------------------------------
// Pass 1 (register-fused MFMA):
//   out_pre[n,o,t,v] = sum_{h,c,u} W[h,o,c] A[h,v,u] x[n,c,t,u]
// GEMM1 per (t,uh): D1[u'][o] = mfma(A=x-frag rows u', B=W-frag cols o), K=c=64.
//   A-frag row m reads u(m) = (m>>2)*8 + uh*4 + (m&3), so lane (l15,hi) ends up
//   holding y[u = hi*8 + uh*4 + j][o = l15] — exactly GEMM2's B-fragment. y
//   never touches LDS.
// GEMM2 per t: acc[v][o] += mfma(A = A_h rows v, B = y-frag), K=u pad 32.
// SCR=1 round-6 change: scratch is WAVE-LINEAR — per (blk,t) a 3584 B tile:
//   vt0: base + w*256 + hi*64 + l15*4 + j          (v = hi*4+j,    o = 16w+l15)
//   vt1: base + 1024 + w*192 + hi*64 + l15*4 + j   (v = 16+hi*4+j, hi<3)
// Each lane's stores are two 8 B COALESCED stores (wave covers contiguous
// 512 B / 384 B) — kills the per-iteration scattered-store retire wait that
// R3-R5 evidence says was the stall. o/v scatter moves to pass 3.
// SCR=0: fp32 scratch = d_out in final layout, scalar stores (fallback).
// bias dropped: per-channel constant cancels exactly through BatchNorm.
// ---------------------------------------------------------------------------
template <int SCR>
__global__ __launch_bounds__(256, 4) void gcn_pass1(
    const float* __restrict__ x, const float* __restrict__ A,
    const float* __restrict__ W, void* __restrict__ scratch_,
    float* __restrict__ partial)
{
    __shared__ __align__(16) short x_sT[XROWS * XPITCH];   // 31,616 B

    const int blk  = blockIdx.x;
    const int n    = blk >> 6;             // 64 t-groups per n
    const int t0   = (blk & 63) * TT;
    const int tid  = threadIdx.x;
    const int lane = tid & 63;
    const int w    = tid >> 6;             // wave 0..3 -> o in [16w, 16w+16)
    const int l15  = lane & 15;
    const int hi   = lane >> 4;

    // ---- W fragments: lane: o = 16w + l15, k(c) = s*32 + hi*8 + i
    bf16x8 wf[H_DIM][2];
    #pragma unroll
    for (int h = 0; h < H_DIM; ++h)
        #pragma unroll
        for (int s = 0; s < 2; ++s) {
            const f32x4* wp = (const f32x4*)(W + h * 4096 + (16 * w + l15) * 64
                                             + s * 32 + hi * 8);
            f32x4 lo = wp[0], hv = wp[1];
            bf16x8 f;
            #pragma unroll
            for (int i = 0; i < 4; ++i) { f[i] = f2bf(lo[i]); f[4 + i] = f2bf(hv[i]); }
            wf[h][s] = f;
        }

    // ---- A fragments: lane: v = vt*16 + l15, k(u) = hi*8 + i; zero pads
    bf16x8 af[H_DIM][2];
    #pragma unroll
    for (int h = 0; h < H_DIM; ++h)
        #pragma unroll
        for (int vt = 0; vt < 2; ++vt) {
            int v = vt * 16 + l15;
            bf16x8 f;
            #pragma unroll
            for (int i = 0; i < 8; ++i) {
                int u = hi * 8 + i;
                f[i] = (v < 25 && u < 25) ? f2bf(A[h * 625 + v * 25 + u]) : (short)0;
            }
            af[h][vt] = f;
        }

    // ---- stage x transposed: x_sT[tu][c], b64 writes, 4 coalesced load streams
    const float* xn = x + (size_t)n * (C_DIM * T_DIM * V_DIM) + t0 * 25;
    for (int e = tid; e < 3200; e += 256) {
        int cg = e / 200, tu = e - cg * 200;
        float f0 = xn[(4 * cg + 0) * 12800 + tu];
        float f1 = xn[(4 * cg + 1) * 12800 + tu];
        float f2 = xn[(4 * cg + 2) * 12800 + tu];
        float f3 = xn[(4 * cg + 3) * 12800 + tu];
        s16x4 p; p[0] = f2bf(f0); p[1] = f2bf(f1); p[2] = f2bf(f2); p[3] = f2bf(f3);
        *(s16x4*)&x_sT[tu * XPITCH + 4 * cg] = p;
    }
    // zero pad rows 200..207 (avoid stale-LDS NaN patterns reaching MFMA)
    for (int e = tid; e < 304; e += 256)
        ((int*)&x_sT[200 * XPITCH])[e] = 0;
    __syncthreads();

    // per-lane x-row base for the u-permutation: u = (l15>>2)*8 + uh*4 + (l15&3)
    const int ubase = ((l15 >> 2) * 8) + (l15 & 3);

    float s_tot = 0.f, q_tot = 0.f;
    const int o_glob = 16 * w + l15;

    #pragma unroll 2
    for (int t = 0; t < TT; ++t) {
        const short* xr0 = &x_sT[(t * 25 + ubase + 0) * XPITCH + hi * 8];  // uh=0
        const short* xr1 = &x_sT[(t * 25 + ubase + 4) * XPITCH + hi * 8];  // uh=1
        const bf16x8 xf00 = ld_bf8(xr0), xf01 = ld_bf8(xr0 + 32);
        const bf16x8 xf10 = ld_bf8(xr1), xf11 = ld_bf8(xr1 + 32);

        f32x4 acc2[2] = {f32x4{0.f, 0.f, 0.f, 0.f}, f32x4{0.f, 0.f, 0.f, 0.f}};

        #pragma unroll
        for (int h = 0; h < H_DIM; ++h) {
            f32x4 y0 = {0.f, 0.f, 0.f, 0.f}, y1 = {0.f, 0.f, 0.f, 0.f};
            y0 = __builtin_amdgcn_mfma_f32_16x16x32_bf16(xf00, wf[h][0], y0, 0, 0, 0);
            y0 = __builtin_amdgcn_mfma_f32_16x16x32_bf16(xf01, wf[h][1], y0, 0, 0, 0);
            y1 = __builtin_amdgcn_mfma_f32_16x16x32_bf16(xf10, wf[h][0], y1, 0, 0, 0);
            y1 = __builtin_amdgcn_mfma_f32_16x16x32_bf16(xf11, wf[h][1], y1, 0, 0, 0);
            bf16x8 yf;
            #pragma unroll
            for (int j = 0; j < 4; ++j) yf[j] = f2bf(y0[j]);
            #pragma unroll
            for (int j = 0; j < 4; ++j) yf[4 + j] = f2bf(y1[j]);
            acc2[0] = __builtin_amdgcn_mfma_f32_16x16x32_bf16(af[h][0], yf, acc2[0], 0, 0, 0);
            acc2[1] = __builtin_amdgcn_mfma_f32_16x16x32_bf16(af[h][1], yf, acc2[1], 0, 0, 0);
        }

        if (SCR) {
            // wave-linear bf16 scratch tile for (blk,t): two coalesced 8B stores
            short* base = (short*)scratch_ + ((size_t)blk * TT + t) * TILE_SH;
            s16x4 p0; p0[0] = f2bf(acc2[0][0]); p0[1] = f2bf(acc2[0][1]);
                      p0[2] = f2bf(acc2[0][2]); p0[3] = f2bf(acc2[0][3]);
            *(s16x4*)(base + w * 256 + hi * 64 + l15 * 4) = p0;
            if (hi < 3) {
                s16x4 p1; p1[0] = f2bf(acc2[1][0]); p1[1] = f2bf(acc2[1][1]);
                          p1[2] = f2bf(acc2[1][2]); p1[3] = f2bf(acc2[1][3]);
                *(s16x4*)(base + 1024 + w * 192 + hi * 64 + l15 * 4) = p1;
            }
        } else {
            float* op = (float*)scratch_
                      + ((size_t)(n * 64 + o_glob) * 512 + (t0 + t)) * 25;
            #pragma unroll
            for (int j = 0; j < 4; ++j) op[hi * 4 + j] = acc2[0][j];
            if (hi < 2) {
                #pragma unroll
                for (int j = 0; j < 4; ++j) op[16 + hi * 4 + j] = acc2[1][j];
            } else if (hi == 2) {
                op[24] = acc2[1][0];
            }
        }

        // ---- per-lane stats accumulate (shuffle hoisted out of loop)
        float s = acc2[0][0] + acc2[0][1] + acc2[0][2] + acc2[0][3];
        float q = fmaf(acc2[0][0], acc2[0][0], fmaf(acc2[0][1], acc2[0][1],
                  fmaf(acc2[0][2], acc2[0][2], acc2[0][3] * acc2[0][3])));
        if (hi < 2) {
            #pragma unroll
            for (int j = 0; j < 4; ++j) {
                float v1 = acc2[1][j]; s += v1; q = fmaf(v1, v1, q);
            }
        } else if (hi == 2) {
            float v1 = acc2[1][0]; s += v1; q = fmaf(v1, v1, q);
        }
        s_tot += s; q_tot += q;
    }

    s_tot += __shfl_xor(s_tot, 16); q_tot += __shfl_xor(q_tot, 16);
    s_tot += __shfl_xor(s_tot, 32); q_tot += __shfl_xor(q_tot, 32);
    if (hi == 0) {
        partial[blk * 128 + o_glob]      = s_tot;
        partial[blk * 128 + 64 + o_glob] = q_tot;
    }
}

// ---------------------------------------------------------------------------
// Pass 2: reduce partials -> per-channel mean and rsqrt(var+eps)
// ---------------------------------------------------------------------------
__global__ __launch_bounds__(256) void gcn_stats(
    const float* __restrict__ partial, float* __restrict__ stats)
{
    const int o = blockIdx.x;      // 64 blocks, one per channel
    const int tid = threadIdx.x;
    float s = 0.f, q = 0.f;
    for (int blk = tid; blk < NBLK; blk += 256) {
        s += partial[blk * 128 + o];
        q += partial[blk * 128 + 64 + o];
    }
    __shared__ float rs[256], rq[256];
    rs[tid] = s; rq[tid] = q;
    __syncthreads();
    for (int off = 128; off > 0; off >>= 1) {
        if (tid < off) { rs[tid] += rs[tid + off]; rq[tid] += rq[tid + off]; }
        __syncthreads();
    }
    if (tid == 0) {
        float mean = rs[0] / (float)NTV;
        float var  = rq[0] / (float)NTV - mean * mean;   // biased, like jnp.var
        stats[o]      = mean;
        stats[64 + o] = rsqrtf(var + BN_EPS);
    }
}

// ---------------------------------------------------------------------------
// Pass 3 (wave-linear scratch): un-scatter + BN + residual + ReLU.
// One block per pass1 block; thread r = tid + rr*256 handles row (o = r>>3,
// tl = r&7): 7x 8B scr group-loads (L3-resident), 25 scalar x reads, 25 writes.
// ---------------------------------------------------------------------------
__global__ __launch_bounds__(256) void gcn_finalize_b(
    const float* __restrict__ x, const float* __restrict__ gamma,
    const float* __restrict__ beta, const float* __restrict__ stats,
    const unsigned short* __restrict__ scr, float* __restrict__ out)
{
    const int blk = blockIdx.x;
    const int n   = blk >> 6;
    const int t0  = (blk & 63) * TT;
    const int tid = threadIdx.x;

    #pragma unroll
    for (int rr = 0; rr < 2; ++rr) {
        int r  = tid + rr * 256;          // 0..511
        int o  = r >> 3;
        int tl = r & 7;
        const unsigned short* tb = scr + ((size_t)blk * TT + tl) * TILE_SH;
        int wq = o >> 4, l = o & 15;

        float pv[28];
        #pragma unroll
        for (int g = 0; g < 4; ++g) {     // v = 4g..4g+3  (vt0, hi=g)
            s16x4 qv = *(const s16x4*)(tb + wq * 256 + g * 64 + l * 4);
            #pragma unroll
            for (int j = 0; j < 4; ++j) pv[4 * g + j] = bf2f(qv[j]);
        }
        #pragma unroll
        for (int g = 0; g < 3; ++g) {     // v = 16+4g..16+4g+3 (vt1, hi=g)
            s16x4 qv = *(const s16x4*)(tb + 1024 + wq * 192 + g * 64 + l * 4);
            #pragma unroll
            for (int j = 0; j < 4; ++j) pv[16 + 4 * g + j] = bf2f(qv[j]);
        }

        float gm = gamma[o] * stats[64 + o];
        float bc = beta[o] - gm * stats[o];
        const float* xr = x + ((size_t)(n * 64 + o) * 512 + t0 + tl) * 25;
        float* orow     = out + ((size_t)(n * 64 + o) * 512 + t0 + tl) * 25;
        #pragma unroll
        for (int v = 0; v < 25; ++v)
            orow[v] = fmaxf(fmaf(gm, pv[v], bc) + xr[v], 0.f);
    }
}

// ---------------------------------------------------------------------------
// Pass 3 (fallback, fp32 scratch == out): in-place elementwise
// ---------------------------------------------------------------------------
__global__ __launch_bounds__(256) void gcn_finalize_f(
    const float* __restrict__ x, const float* __restrict__ gamma,
    const float* __restrict__ beta, const float* __restrict__ stats,
    float* __restrict__ out)
{
    const int total4 = NTOT / 4;
    for (int i = blockIdx.x * blockDim.x + threadIdx.x; i < total4;
         i += gridDim.x * blockDim.x) {
        int chan = ((i * 4) / (T_DIM * V_DIM)) & 63;
        float4 p  = ((const float4*)out)[i];
        float4 xv = ((const float4*)x)[i];
        float m = stats[chan], r = stats[64 + chan];
        float g = gamma[chan] * r;
        float bc = beta[chan] - g * m;
        p.x = fmaxf(fmaf(g, p.x, bc) + xv.x, 0.f);
        p.y = fmaxf(fmaf(g, p.y, bc) + xv.y, 0.f);
        p.z = fmaxf(fmaf(g, p.z, bc) + xv.z, 0.f);
        p.w = fmaxf(fmaf(g, p.w, bc) + xv.w, 0.f);
        ((float4*)out)[i] = p;
    }
}

extern "C" void kernel_launch(void* const* d_in, const int* in_sizes, int n_in,
                              void* d_out, int out_size, void* d_ws, size_t ws_size,
                              hipStream_t stream) {
    const float* x     = (const float*)d_in[0];
    const float* A     = (const float*)d_in[1];
    const float* W     = (const float*)d_in[2];
    // d_in[3] = b : unused — per-channel bias cancels exactly through BatchNorm
    const float* gamma = (const float*)d_in[4];
    const float* beta  = (const float*)d_in[5];
    float* out = (float*)d_out;

    const size_t scr_bytes  = (size_t)NBLK * TT * TILE_SH * 2;   // 58.7 MB (as before)
    const size_t part_bytes = (size_t)(NBLK * 128 + 128) * 4;    // 1.0 MB

    if (ws_size >= scr_bytes + part_bytes) {
        unsigned short* scr = (unsigned short*)d_ws;
        float* partial = (float*)((char*)d_ws + scr_bytes);
        float* stats   = partial + NBLK * 128;
        gcn_pass1<1><<<NBLK, 256, 0, stream>>>(x, A, W, (void*)scr, partial);
        gcn_stats<<<64, 256, 0, stream>>>(partial, stats);
        gcn_finalize_b<<<NBLK, 256, 0, stream>>>(x, gamma, beta, stats, scr, out);
    } else {
        float* partial = (float*)d_ws;
        float* stats   = partial + NBLK * 128;
        gcn_pass1<0><<<NBLK, 256, 0, stream>>>(x, A, W, (void*)out, partial);
        gcn_stats<<<64, 256, 0, stream>>>(partial, stats);
        gcn_finalize_f<<<2048, 256, 0, stream>>>(x, gamma, beta, stats, out);
    }
}

// Round 7
// 91.989 us; speedup vs baseline: 1.6811x; 1.5056x over previous
//
#include <hip/hip_runtime.h>
#include <hip/hip_bf16.h>

// Problem dims (fixed by the reference)
#define N_DIM 32
#define C_DIM 64
#define T_DIM 512
#define V_DIM 25
#define H_DIM 3
#define TT 8                              // t-values per t-group
#define GPB 4                             // t-groups per pass1 block
#define NBLK1 512                         // pass1 blocks (= 2/CU exactly)
#define NTGRP 2048                        // total t-groups (= pass3 blocks)
#define NTV (N_DIM * T_DIM * V_DIM)       // 409600 elements per channel
#define NTOT (N_DIM * C_DIM * T_DIM * V_DIM)
#define XPITCH 76                         // shorts per tu-row (152 B)
#define XROWS 208                         // 200 data rows + 8 zero-pad
#define TILE_SH 1792                      // shorts per (tgrp,t) scratch tile (3584 B)
#define BN_EPS 1e-5f

typedef float f32x4 __attribute__((ext_vector_type(4)));
typedef short bf16x8 __attribute__((ext_vector_type(8)));
typedef short s16x4 __attribute__((ext_vector_type(4)));

__device__ __forceinline__ short f2bf(float f) {
    __hip_bfloat16 h = __float2bfloat16(f);   // RNE; pairs fuse to v_cvt_pk_bf16_f32
    return __builtin_bit_cast(short, h);
}
__device__ __forceinline__ float bf2f(short s) {
    return __uint_as_float(((unsigned)(unsigned short)s) << 16);
}

__device__ __forceinline__ bf16x8 ld_bf8(const short* p) {   // two b64 LDS reads
    s16x4 a = *(const s16x4*)p;
    s16x4 b = *(const s16x4*)(p + 4);
    bf16x8 r;
    r[0] = a[0]; r[1] = a[1]; r[2] = a[2]; r[3] = a[3];
    r[4] = b[0]; r[5] = b[1]; r[6] = b[2]; r[7] = b[3];
    return r;
}

// ---------------------------------------------------------------------------
// Pass 0: pack W and A into per-thread MFMA fragment layout (bf16).
// wpack[b=h*2+s][tid] : o = 16*(tid>>6)+(tid&15), c = s*32+((tid>>4)&3)*8+i
// apack[b=h*2+vt][tid]: v = vt*16+(tid&15),       u = ((tid>>4)&3)*8+i  (0-pad)
// Turns pass1's ~60 scattered per-thread loads into 12 coalesced 16B loads.
// ---------------------------------------------------------------------------
__global__ __launch_bounds__(256) void gcn_pack(
    const float* __restrict__ A, const float* __restrict__ W,
    short* __restrict__ wpack, short* __restrict__ apack)
{
    const int b   = blockIdx.x;           // 0..11
    const int tid = threadIdx.x;
    const int l15 = tid & 15, hi = (tid >> 4) & 3, w = tid >> 6;
    if (b < 6) {
        int h = b >> 1, s = b & 1;
        const float* wp = W + h * 4096 + (16 * w + l15) * 64 + s * 32 + hi * 8;
        bf16x8 f;
        #pragma unroll
        for (int i = 0; i < 8; ++i) f[i] = f2bf(wp[i]);
        *(bf16x8*)(wpack + ((size_t)b * 256 + tid) * 8) = f;
    } else {
        int bb = b - 6, h = bb >> 1, vt = bb & 1;
        int v = vt * 16 + l15;
        bf16x8 f;
        #pragma unroll
        for (int i = 0; i < 8; ++i) {
            int u = hi * 8 + i;
            f[i] = (v < 25 && u < 25) ? f2bf(A[h * 625 + v * 25 + u]) : (short)0;
        }
        *(bf16x8*)(apack + ((size_t)bb * 256 + tid) * 8) = f;
    }
}

// ---- stage one t-group's x tile (transposed bf16) into LDS buffer
__device__ __forceinline__ void stage_to(short* __restrict__ dst,
                                         const float* __restrict__ xg, int tid)
{
    #pragma unroll 4
    for (int e = tid; e < 3200; e += 256) {
        int cg = e / 200;
        int tu = e - cg * 200;
        const float* p = xg + cg * 51200 + tu;   // 4 c-rows per cg
        float f0 = p[0], f1 = p[12800], f2 = p[25600], f3 = p[38400];
        s16x4 v; v[0] = f2bf(f0); v[1] = f2bf(f1); v[2] = f2bf(f2); v[3] = f2bf(f3);
        *(s16x4*)&dst[tu * XPITCH + 4 * cg] = v;
    }
}

// ---------------------------------------------------------------------------
// Pass 1 (register-fused MFMA, 512 blocks x 4 t-groups, double-buffered LDS):
//   out_pre[n,o,t,v] = sum_{h,c,u} W[h,o,c] A[h,v,u] x[n,c,t,u]
// GEMM1 per (t,uh): D1[u'][o] = mfma(A=x rows u', B=W cols o), K=c=64; the
//   u-permutation u(m) = (m>>2)*8 + uh*4 + (m&3) makes lane (l15,hi) hold
//   y[u=hi*8+uh*4+j][o=l15] — exactly GEMM2's B-fragment, in registers.
// GEMM2 per t: acc[v][o] += mfma(A = A_h rows v, B = y-frag), K=u pad 32.
// Group g+1's staging loads issue BEFORE group g's compute (latency hides
// under MFMAs); ds_writes target the other buffer so no extra barrier.
// SCR=1: wave-linear bf16 scratch tiles (two coalesced 8B stores per lane).
// SCR=0: fp32 direct to d_out (fallback; in-kernel fragment build).
// bias dropped: per-channel constant cancels exactly through BatchNorm.
// ---------------------------------------------------------------------------
template <int SCR>
__global__ __launch_bounds__(256, 2) void gcn_pass1(
    const float* __restrict__ x, const float* __restrict__ A,
    const float* __restrict__ W, const short* __restrict__ wpack,
    const short* __restrict__ apack, void* __restrict__ scratch_,
    float* __restrict__ partial)
{
    __shared__ __align__(16) short x_sT[2][XROWS * XPITCH];   // 63,232 B

    const int bg   = blockIdx.x;
    const int n    = bg >> 4;              // 16 blocks per n
    const int q    = bg & 15;              // 4 t-groups: tgrp = q*4+g
    const int tid  = threadIdx.x;
    const int lane = tid & 63;
    const int w    = tid >> 6;             // wave 0..3 -> o in [16w, 16w+16)
    const int l15  = lane & 15;
    const int hi   = lane >> 4;

    bf16x8 wf[H_DIM][2], af[H_DIM][2];
    if constexpr (SCR) {
        #pragma unroll
        for (int h = 0; h < H_DIM; ++h)
            #pragma unroll
            for (int s = 0; s < 2; ++s) {
                wf[h][s] = *(const bf16x8*)(wpack + ((h * 2 + s) * 256 + tid) * 8);
                af[h][s] = *(const bf16x8*)(apack + ((h * 2 + s) * 256 + tid) * 8);
            }
    } else {
        #pragma unroll
        for (int h = 0; h < H_DIM; ++h)
            #pragma unroll
            for (int s = 0; s < 2; ++s) {
                const f32x4* wp = (const f32x4*)(W + h * 4096 + (16 * w + l15) * 64
                                                 + s * 32 + hi * 8);
                f32x4 lo = wp[0], hv = wp[1];
                bf16x8 f;
                #pragma unroll
                for (int i = 0; i < 4; ++i) { f[i] = f2bf(lo[i]); f[4+i] = f2bf(hv[i]); }
                wf[h][s] = f;
                int v = s * 16 + l15;
                bf16x8 g;
                #pragma unroll
                for (int i = 0; i < 8; ++i) {
                    int u = hi * 8 + i;
                    g[i] = (v < 25 && u < 25) ? f2bf(A[h * 625 + v * 25 + u]) : (short)0;
                }
                af[h][s] = g;
            }
    }

    // zero pad rows 200..207 of both buffers (never written by staging)
    for (int e = tid; e < 304; e += 256) {
        ((int*)&x_sT[0][200 * XPITCH])[e] = 0;
        ((int*)&x_sT[1][200 * XPITCH])[e] = 0;
    }
    const float* xn = x + (size_t)n * 819200;
    stage_to(&x_sT[0][0], xn + (q * 4 + 0) * 200, tid);
    __syncthreads();

    // per-lane x-row base for the u-permutation: u = (l15>>2)*8 + uh*4 + (l15&3)
    const int ubase = ((l15 >> 2) * 8) + (l15 & 3);
    const int o_glob = 16 * w + l15;
    float s_tot = 0.f, q_tot = 0.f;

    for (int g = 0; g < GPB; ++g) {
        const int tgrp = q * 4 + g;
        const short* cbuf = &x_sT[g & 1][0];
        if (g < GPB - 1)                                  // async-stage next group
            stage_to(&x_sT[(g + 1) & 1][0], xn + (tgrp + 1) * 200, tid);

        #pragma unroll 2
        for (int t = 0; t < TT; ++t) {
            const short* xr0 = &cbuf[(t * 25 + ubase + 0) * XPITCH + hi * 8];
            const short* xr1 = &cbuf[(t * 25 + ubase + 4) * XPITCH + hi * 8];
            const bf16x8 xf00 = ld_bf8(xr0), xf01 = ld_bf8(xr0 + 32);
            const bf16x8 xf10 = ld_bf8(xr1), xf11 = ld_bf8(xr1 + 32);

            f32x4 acc2[2] = {f32x4{0.f,0.f,0.f,0.f}, f32x4{0.f,0.f,0.f,0.f}};

            #pragma unroll
            for (int h = 0; h < H_DIM; ++h) {
                f32x4 y0 = {0.f,0.f,0.f,0.f}, y1 = {0.f,0.f,0.f,0.f};
                y0 = __builtin_amdgcn_mfma_f32_16x16x32_bf16(xf00, wf[h][0], y0, 0,0,0);
                y0 = __builtin_amdgcn_mfma_f32_16x16x32_bf16(xf01, wf[h][1], y0, 0,0,0);
                y1 = __builtin_amdgcn_mfma_f32_16x16x32_bf16(xf10, wf[h][0], y1, 0,0,0);
                y1 = __builtin_amdgcn_mfma_f32_16x16x32_bf16(xf11, wf[h][1], y1, 0,0,0);
                bf16x8 yf;
                #pragma unroll
                for (int j = 0; j < 4; ++j) yf[j] = f2bf(y0[j]);
                #pragma unroll
                for (int j = 0; j < 4; ++j) yf[4 + j] = f2bf(y1[j]);
                acc2[0] = __builtin_amdgcn_mfma_f32_16x16x32_bf16(af[h][0], yf, acc2[0], 0,0,0);
                acc2[1] = __builtin_amdgcn_mfma_f32_16x16x32_bf16(af[h][1], yf, acc2[1], 0,0,0);
            }

            if (SCR) {
                // wave-linear bf16 tile: two coalesced 8B stores per lane
                short* base = (short*)scratch_
                            + ((size_t)((n * 64 + tgrp) * 8 + t)) * TILE_SH;
                s16x4 p0; p0[0]=f2bf(acc2[0][0]); p0[1]=f2bf(acc2[0][1]);
                          p0[2]=f2bf(acc2[0][2]); p0[3]=f2bf(acc2[0][3]);
                *(s16x4*)(base + w * 256 + hi * 64 + l15 * 4) = p0;
                if (hi < 3) {
                    s16x4 p1; p1[0]=f2bf(acc2[1][0]); p1[1]=f2bf(acc2[1][1]);
                              p1[2]=f2bf(acc2[1][2]); p1[3]=f2bf(acc2[1][3]);
                    *(s16x4*)(base + 1024 + w * 192 + hi * 64 + l15 * 4) = p1;
                }
            } else {
                float* op = (float*)scratch_
                          + ((size_t)(n * 64 + o_glob) * 512 + tgrp * 8 + t) * 25;
                #pragma unroll
                for (int j = 0; j < 4; ++j) op[hi * 4 + j] = acc2[0][j];
                if (hi < 2) {
                    #pragma unroll
                    for (int j = 0; j < 4; ++j) op[16 + hi * 4 + j] = acc2[1][j];
                } else if (hi == 2) {
                    op[24] = acc2[1][0];
                }
            }

            // ---- per-lane stats accumulate (shuffle hoisted to epilogue)
            float s = acc2[0][0] + acc2[0][1] + acc2[0][2] + acc2[0][3];
            float qq = fmaf(acc2[0][0], acc2[0][0], fmaf(acc2[0][1], acc2[0][1],
                       fmaf(acc2[0][2], acc2[0][2], acc2[0][3] * acc2[0][3])));
            if (hi < 2) {
                #pragma unroll
                for (int j = 0; j < 4; ++j) {
                    float v1 = acc2[1][j]; s += v1; qq = fmaf(v1, v1, qq);
                }
            } else if (hi == 2) {
                float v1 = acc2[1][0]; s += v1; qq = fmaf(v1, v1, qq);
            }
            s_tot += s; q_tot += qq;
        }
        __syncthreads();   // next buffer staged AND current reads done
    }

    s_tot += __shfl_xor(s_tot, 16); q_tot += __shfl_xor(q_tot, 16);
    s_tot += __shfl_xor(s_tot, 32); q_tot += __shfl_xor(q_tot, 32);
    if (hi == 0) {
        partial[bg * 128 + o_glob]      = s_tot;
        partial[bg * 128 + 64 + o_glob] = q_tot;
    }
}

// ---------------------------------------------------------------------------
// Pass 2: reduce partials -> per-channel mean and rsqrt(var+eps)
// ---------------------------------------------------------------------------
__global__ __launch_bounds__(256) void gcn_stats(
    const float* __restrict__ partial, float* __restrict__ stats)
{
    const int o = blockIdx.x;      // 64 blocks, one per channel
    const int tid = threadIdx.x;
    float s = 0.f, q = 0.f;
    for (int blk = tid; blk < NBLK1; blk += 256) {
        s += partial[blk * 128 + o];
        q += partial[blk * 128 + 64 + o];
    }
    __shared__ float rs[256], rq[256];
    rs[tid] = s; rq[tid] = q;
    __syncthreads();
    for (int off = 128; off > 0; off >>= 1) {
        if (tid < off) { rs[tid] += rs[tid + off]; rq[tid] += rq[tid + off]; }
        __syncthreads();
    }
    if (tid == 0) {
        float mean = rs[0] / (float)NTV;
        float var  = rq[0] / (float)NTV - mean * mean;   // biased, like jnp.var
        stats[o]      = mean;
        stats[64 + o] = rsqrtf(var + BN_EPS);
    }
}

// ---------------------------------------------------------------------------
// Pass 3: un-scatter via LDS + BN + residual + ReLU, fully coalesced float4.
// One block per t-group: copy its 8 tiles (28,672 B) into LDS with int4
// (7 coalesced loads/thread), then stream the 64 o-runs x 200 contiguous
// floats as float4 (x read / out write coalesced; LDS lookups cheap).
// ---------------------------------------------------------------------------
__global__ __launch_bounds__(256) void gcn_finalize_b(
    const float* __restrict__ x, const float* __restrict__ gamma,
    const float* __restrict__ beta, const float* __restrict__ stats,
    const short* __restrict__ scr, float* __restrict__ out)
{
    __shared__ __align__(16) short tl_s[8 * TILE_SH];   // 28,672 B
    const int bid  = blockIdx.x;           // 0..2047
    const int n    = bid >> 6;
    const int tgrp = bid & 63;
    const int tid  = threadIdx.x;

    const int4* src = (const int4*)(scr + (size_t)bid * 8 * TILE_SH);
    int4* dst4 = (int4*)tl_s;
    #pragma unroll
    for (int k = 0; k < 7; ++k) dst4[tid + k * 256] = src[tid + k * 256]; // 1792
    __syncthreads();

    const size_t obase = (size_t)n * 819200 + (size_t)tgrp * 200;
    #pragma unroll
    for (int k = 0; k < 13; ++k) {
        int fi = tid + k * 256;
        if (fi < 3200) {
            int o  = fi / 50;                 // 50 float4 per o-run
            int p  = (fi - o * 50) * 4;       // 0..196
            int tl = p / 25;
            int v0 = p - tl * 25;
            float gm = gamma[o] * stats[64 + o];
            float bc = beta[o] - gm * stats[o];
            size_t gidx = obase + (size_t)o * 12800 + p;
            float4 xv = *(const float4*)(x + gidx);
            float r[4];
            #pragma unroll
            for (int j = 0; j < 4; ++j) {
                int vv = v0 + j, tt = tl;
                if (vv >= 25) { vv -= 25; tt += 1; }
                int off = (vv < 16)
                    ? ((o >> 4) * 256 + (vv >> 2) * 64 + (o & 15) * 4 + (vv & 3))
                    : (1024 + (o >> 4) * 192 + ((vv - 16) >> 2) * 64
                       + (o & 15) * 4 + (vv & 3));
                float pv = bf2f(tl_s[tt * TILE_SH + off]);
                r[j] = fmaxf(fmaf(gm, pv, bc) + (&xv.x)[j], 0.f);
            }
            float4 o4; o4.x = r[0]; o4.y = r[1]; o4.z = r[2]; o4.w = r[3];
            *(float4*)(out + gidx) = o4;
        }
    }
}

// ---------------------------------------------------------------------------
// Pass 3 (fallback, fp32 scratch == out): in-place elementwise
// ---------------------------------------------------------------------------
__global__ __launch_bounds__(256) void gcn_finalize_f(
    const float* __restrict__ x, const float* __restrict__ gamma,
    const float* __restrict__ beta, const float* __restrict__ stats,
    float* __restrict__ out)
{
    const int total4 = NTOT / 4;
    for (int i = blockIdx.x * blockDim.x + threadIdx.x; i < total4;
         i += gridDim.x * blockDim.x) {
        int chan = ((i * 4) / (T_DIM * V_DIM)) & 63;
        float4 p  = ((const float4*)out)[i];
        float4 xv = ((const float4*)x)[i];
        float m = stats[chan], r = stats[64 + chan];
        float g = gamma[chan] * r;
        float bc = beta[chan] - g * m;
        p.x = fmaxf(fmaf(g, p.x, bc) + xv.x, 0.f);
        p.y = fmaxf(fmaf(g, p.y, bc) + xv.y, 0.f);
        p.z = fmaxf(fmaf(g, p.z, bc) + xv.z, 0.f);
        p.w = fmaxf(fmaf(g, p.w, bc) + xv.w, 0.f);
        ((float4*)out)[i] = p;
    }
}

extern "C" void kernel_launch(void* const* d_in, const int* in_sizes, int n_in,
                              void* d_out, int out_size, void* d_ws, size_t ws_size,
                              hipStream_t stream) {
    const float* x     = (const float*)d_in[0];
    const float* A     = (const float*)d_in[1];
    const float* W     = (const float*)d_in[2];
    // d_in[3] = b : unused — per-channel bias cancels exactly through BatchNorm
    const float* gamma = (const float*)d_in[4];
    const float* beta  = (const float*)d_in[5];
    float* out = (float*)d_out;

    const size_t scr_bytes   = (size_t)NTGRP * 8 * TILE_SH * 2;  // 58,720,256
    const size_t part_bytes  = (size_t)NBLK1 * 128 * 4;          // 262,144
    const size_t stats_bytes = 512;
    const size_t pack_bytes  = 2 * 6 * 256 * 8 * 2;              // 49,152

    if (ws_size >= scr_bytes + part_bytes + stats_bytes + pack_bytes) {
        short* scr     = (short*)d_ws;
        float* partial = (float*)((char*)d_ws + scr_bytes);
        float* stats   = partial + NBLK1 * 128;
        short* wpack   = (short*)((char*)d_ws + scr_bytes + part_bytes + stats_bytes);
        short* apack   = wpack + 6 * 256 * 8;

        gcn_pack<<<12, 256, 0, stream>>>(A, W, wpack, apack);
        gcn_pass1<1><<<NBLK1, 256, 0, stream>>>(x, A, W, wpack, apack,
                                                (void*)scr, partial);
        gcn_stats<<<64, 256, 0, stream>>>(partial, stats);
        gcn_finalize_b<<<NTGRP, 256, 0, stream>>>(x, gamma, beta, stats, scr, out);
    } else {
        float* partial = (float*)d_ws;
        float* stats   = partial + NBLK1 * 128;
        gcn_pass1<0><<<NBLK1, 256, 0, stream>>>(x, A, W, nullptr, nullptr,
                                                (void*)out, partial);
        gcn_stats<<<64, 256, 0, stream>>>(partial, stats);
        gcn_finalize_f<<<2048, 256, 0, stream>>>(x, gamma, beta, stats, out);
    }
}

// Round 8
// 88.407 us; speedup vs baseline: 1.7492x; 1.0405x over previous
//
#include <hip/hip_runtime.h>
#include <hip/hip_bf16.h>

// Problem dims (fixed by the reference)
#define N_DIM 32
#define C_DIM 64
#define T_DIM 512
#define V_DIM 25
#define H_DIM 3
#define TT 8                              // t-values per t-group
#define GPB 4                             // t-groups per pass1 block
#define NBLK1 512                         // pass1 blocks (= 2/CU exactly)
#define NTGRP 2048                        // pass3 blocks (8-t groups)
#define NTV (N_DIM * T_DIM * V_DIM)       // 409600 elements per channel
#define NTOT (N_DIM * C_DIM * T_DIM * V_DIM)
#define XPITCH 76                         // shorts per tu-row (152 B)
#define XROWS 208                         // 200 data rows + 8 zero-pad
#define TILE_SH 1792                      // shorts per (n,t) scratch tile (3584 B)
#define SITER 13                          // staging iters (3200 / 256, ceil)
#define BN_EPS 1e-5f

typedef float f32x4 __attribute__((ext_vector_type(4)));
typedef short bf16x8 __attribute__((ext_vector_type(8)));
typedef short s16x4 __attribute__((ext_vector_type(4)));

__device__ __forceinline__ short f2bf(float f) {
    __hip_bfloat16 h = __float2bfloat16(f);   // RNE; pairs fuse to v_cvt_pk_bf16_f32
    return __builtin_bit_cast(short, h);
}
__device__ __forceinline__ float bf2f(short s) {
    return __uint_as_float(((unsigned)(unsigned short)s) << 16);
}

__device__ __forceinline__ bf16x8 ld_bf8(const short* p) {   // two b64 LDS reads
    s16x4 a = *(const s16x4*)p;
    s16x4 b = *(const s16x4*)(p + 4);
    bf16x8 r;
    r[0] = a[0]; r[1] = a[1]; r[2] = a[2]; r[3] = a[3];
    r[4] = b[0]; r[5] = b[1]; r[6] = b[2]; r[7] = b[3];
    return r;
}

// ---------------------------------------------------------------------------
// Pass 0: pack W and A into per-thread MFMA fragment layout (bf16).
// wpack[b=h*2+s][tid] : o = 16*(tid>>6)+(tid&15), c = s*32+((tid>>4)&3)*8+i
// apack[b=h*2+vt][tid]: v = vt*16+(tid&15),       u = ((tid>>4)&3)*8+i  (0-pad)
// ---------------------------------------------------------------------------
__global__ __launch_bounds__(256) void gcn_pack(
    const float* __restrict__ A, const float* __restrict__ W,
    short* __restrict__ wpack, short* __restrict__ apack)
{
    const int b   = blockIdx.x;           // 0..11
    const int tid = threadIdx.x;
    const int l15 = tid & 15, hi = (tid >> 4) & 3, w = tid >> 6;
    if (b < 6) {
        int h = b >> 1, s = b & 1;
        const float* wp = W + h * 4096 + (16 * w + l15) * 64 + s * 32 + hi * 8;
        bf16x8 f;
        #pragma unroll
        for (int i = 0; i < 8; ++i) f[i] = f2bf(wp[i]);
        *(bf16x8*)(wpack + ((size_t)b * 256 + tid) * 8) = f;
    } else {
        int bb = b - 6, h = bb >> 1, vt = bb & 1;
        int v = vt * 16 + l15;
        bf16x8 f;
        #pragma unroll
        for (int i = 0; i < 8; ++i) {
            int u = hi * 8 + i;
            f[i] = (v < 25 && u < 25) ? f2bf(A[h * 625 + v * 25 + u]) : (short)0;
        }
        *(bf16x8*)(apack + ((size_t)bb * 256 + tid) * 8) = f;
    }
}

// ---- T14 issue-early: launch one t-group's 52 global loads into registers,
//      NO waits (consumed only by stage_write, after the compute phase).
__device__ __forceinline__ void stage_load(float (&fr)[SITER][4],
                                           const float* __restrict__ xg, int tid)
{
    #pragma unroll
    for (int k = 0; k < SITER; ++k) {
        int e = tid + k * 256;
        if (k < SITER - 1 || e < 3200) {
            int cg = e / 200, tu = e - cg * 200;
            const float* p = xg + cg * 51200 + tu;   // 4 c-rows per cg
            fr[k][0] = p[0];
            fr[k][1] = p[12800];
            fr[k][2] = p[25600];
            fr[k][3] = p[38400];
        }
    }
}
// ---- T14 write-late: vmcnt drains here, then convert + coalesced ds_write
__device__ __forceinline__ void stage_write(const float (&fr)[SITER][4],
                                            short* __restrict__ dst, int tid)
{
    #pragma unroll
    for (int k = 0; k < SITER; ++k) {
        int e = tid + k * 256;
        if (k < SITER - 1 || e < 3200) {
            int cg = e / 200, tu = e - cg * 200;
            s16x4 v; v[0] = f2bf(fr[k][0]); v[1] = f2bf(fr[k][1]);
                     v[2] = f2bf(fr[k][2]); v[3] = f2bf(fr[k][3]);
            *(s16x4*)&dst[tu * XPITCH + 4 * cg] = v;
        }
    }
}

// ---------------------------------------------------------------------------
// Pass 1 (register-fused MFMA, double-buffered LDS, T14 split staging):
//   out_pre[n,o,t,v] = sum_{h,c,u} W[h,o,c] A[h,v,u] x[n,c,t,u]
// GEMM1 per (t,uh): D1[u'][o] = mfma(A=x rows u', B=W cols o), K=c=64; the
//   u-permutation u(m) = (m>>2)*8 + uh*4 + (m&3) makes lane (l15,hi) hold
//   y[u=hi*8+uh*4+j][o=l15] — exactly GEMM2's B-fragment, in registers.
// GEMM2 per t: acc[v][o] += mfma(A = A_h rows v, B = y-frag), K=u pad 32.
// Per group: loads for g+1 ISSUE before compute of g (latency hides under
// MFMAs); the vmcnt drain + ds_write happen AFTER compute, into the other
// buffer; one barrier per group.
// SCR=1: wave-linear bf16 scratch tiles [n][t_abs] (coalesced 8B stores).
// SCR=0: fp32 direct to d_out (fallback; in-kernel fragment build).
// bias dropped: per-channel constant cancels exactly through BatchNorm.
// ---------------------------------------------------------------------------
template <int SCR>
__global__ __launch_bounds__(256, 2) void gcn_pass1(
    const float* __restrict__ x, const float* __restrict__ A,
    const float* __restrict__ W, const short* __restrict__ wpack,
    const short* __restrict__ apack, void* __restrict__ scratch_,
    float* __restrict__ partial)
{
    __shared__ __align__(16) short x_sT[2][XROWS * XPITCH];   // 63,232 B

    const int bg   = blockIdx.x;
    const int n    = bg >> 4;              // 16 blocks per n
    const int q    = bg & 15;              // t-groups tgrp = q*4+g
    const int tid  = threadIdx.x;
    const int lane = tid & 63;
    const int w    = tid >> 6;             // wave 0..3 -> o in [16w, 16w+16)
    const int l15  = lane & 15;
    const int hi   = lane >> 4;

    bf16x8 wf[H_DIM][2], af[H_DIM][2];
    if constexpr (SCR) {
        #pragma unroll
        for (int h = 0; h < H_DIM; ++h)
            #pragma unroll
            for (int s = 0; s < 2; ++s) {
                wf[h][s] = *(const bf16x8*)(wpack + ((h * 2 + s) * 256 + tid) * 8);
                af[h][s] = *(const bf16x8*)(apack + ((h * 2 + s) * 256 + tid) * 8);
            }
    } else {
        #pragma unroll
        for (int h = 0; h < H_DIM; ++h)
            #pragma unroll
            for (int s = 0; s < 2; ++s) {
                const f32x4* wp = (const f32x4*)(W + h * 4096 + (16 * w + l15) * 64
                                                 + s * 32 + hi * 8);
                f32x4 lo = wp[0], hv = wp[1];
                bf16x8 f;
                #pragma unroll
                for (int i = 0; i < 4; ++i) { f[i] = f2bf(lo[i]); f[4+i] = f2bf(hv[i]); }
                wf[h][s] = f;
                int v = s * 16 + l15;
                bf16x8 g;
                #pragma unroll
                for (int i = 0; i < 8; ++i) {
                    int u = hi * 8 + i;
                    g[i] = (v < 25 && u < 25) ? f2bf(A[h * 625 + v * 25 + u]) : (short)0;
                }
                af[h][s] = g;
            }
    }

    // zero pad rows 200..207 of both buffers (never written by staging)
    for (int e = tid; e < 304; e += 256) {
        ((int*)&x_sT[0][200 * XPITCH])[e] = 0;
        ((int*)&x_sT[1][200 * XPITCH])[e] = 0;
    }

    const float* xn = x + (size_t)n * 819200;
    float fr[SITER][4];

    // prologue: stage group 0 (latency exposed once per block)
    stage_load(fr, xn + (q * GPB + 0) * 200, tid);
    stage_write(fr, &x_sT[0][0], tid);
    __syncthreads();

    // per-lane x-row base for the u-permutation: u = (l15>>2)*8 + uh*4 + (l15&3)
    const int ubase = ((l15 >> 2) * 8) + (l15 & 3);
    const int o_glob = 16 * w + l15;
    float s_tot = 0.f, q_tot = 0.f;

    for (int g = 0; g < GPB; ++g) {
        const int tgrp = q * GPB + g;
        const short* cbuf = &x_sT[g & 1][0];

        if (g < GPB - 1)                      // ISSUE next group's loads (no wait)
            stage_load(fr, xn + (tgrp + 1) * 200, tid);

        #pragma unroll 2
        for (int t = 0; t < TT; ++t) {
            const short* xr0 = &cbuf[(t * 25 + ubase + 0) * XPITCH + hi * 8];
            const short* xr1 = &cbuf[(t * 25 + ubase + 4) * XPITCH + hi * 8];
            const bf16x8 xf00 = ld_bf8(xr0), xf01 = ld_bf8(xr0 + 32);
            const bf16x8 xf10 = ld_bf8(xr1), xf11 = ld_bf8(xr1 + 32);

            f32x4 acc2[2] = {f32x4{0.f,0.f,0.f,0.f}, f32x4{0.f,0.f,0.f,0.f}};

            #pragma unroll
            for (int h = 0; h < H_DIM; ++h) {
                f32x4 y0 = {0.f,0.f,0.f,0.f}, y1 = {0.f,0.f,0.f,0.f};
                y0 = __builtin_amdgcn_mfma_f32_16x16x32_bf16(xf00, wf[h][0], y0, 0,0,0);
                y0 = __builtin_amdgcn_mfma_f32_16x16x32_bf16(xf01, wf[h][1], y0, 0,0,0);
                y1 = __builtin_amdgcn_mfma_f32_16x16x32_bf16(xf10, wf[h][0], y1, 0,0,0);
                y1 = __builtin_amdgcn_mfma_f32_16x16x32_bf16(xf11, wf[h][1], y1, 0,0,0);
                bf16x8 yf;
                #pragma unroll
                for (int j = 0; j < 4; ++j) yf[j] = f2bf(y0[j]);
                #pragma unroll
                for (int j = 0; j < 4; ++j) yf[4 + j] = f2bf(y1[j]);
                acc2[0] = __builtin_amdgcn_mfma_f32_16x16x32_bf16(af[h][0], yf, acc2[0], 0,0,0);
                acc2[1] = __builtin_amdgcn_mfma_f32_16x16x32_bf16(af[h][1], yf, acc2[1], 0,0,0);
            }

            if (SCR) {
                // wave-linear bf16 tile [n][t_abs]: two coalesced 8B stores
                short* base = (short*)scratch_
                            + ((size_t)(n * 512 + tgrp * TT + t)) * TILE_SH;
                s16x4 p0; p0[0]=f2bf(acc2[0][0]); p0[1]=f2bf(acc2[0][1]);
                          p0[2]=f2bf(acc2[0][2]); p0[3]=f2bf(acc2[0][3]);
                *(s16x4*)(base + w * 256 + hi * 64 + l15 * 4) = p0;
                if (hi < 3) {
                    s16x4 p1; p1[0]=f2bf(acc2[1][0]); p1[1]=f2bf(acc2[1][1]);
                              p1[2]=f2bf(acc2[1][2]); p1[3]=f2bf(acc2[1][3]);
                    *(s16x4*)(base + 1024 + w * 192 + hi * 64 + l15 * 4) = p1;
                }
            } else {
                float* op = (float*)scratch_
                          + ((size_t)(n * 64 + o_glob) * 512 + tgrp * TT + t) * 25;
                #pragma unroll
                for (int j = 0; j < 4; ++j) op[hi * 4 + j] = acc2[0][j];
                if (hi < 2) {
                    #pragma unroll
                    for (int j = 0; j < 4; ++j) op[16 + hi * 4 + j] = acc2[1][j];
                } else if (hi == 2) {
                    op[24] = acc2[1][0];
                }
            }

            // ---- per-lane stats accumulate (shuffle hoisted to epilogue)
            float s = acc2[0][0] + acc2[0][1] + acc2[0][2] + acc2[0][3];
            float qq = fmaf(acc2[0][0], acc2[0][0], fmaf(acc2[0][1], acc2[0][1],
                       fmaf(acc2[0][2], acc2[0][2], acc2[0][3] * acc2[0][3])));
            if (hi < 2) {
                #pragma unroll
                for (int j = 0; j < 4; ++j) {
                    float v1 = acc2[1][j]; s += v1; qq = fmaf(v1, v1, qq);
                }
            } else if (hi == 2) {
                float v1 = acc2[1][0]; s += v1; qq = fmaf(v1, v1, qq);
            }
            s_tot += s; q_tot += qq;
        }

        if (g < GPB - 1)                      // WRITE-LATE: drain + ds_write other buf
            stage_write(fr, &x_sT[(g + 1) & 1][0], tid);
        __syncthreads();
    }

    s_tot += __shfl_xor(s_tot, 16); q_tot += __shfl_xor(q_tot, 16);
    s_tot += __shfl_xor(s_tot, 32); q_tot += __shfl_xor(q_tot, 32);
    if (hi == 0) {
        partial[bg * 128 + o_glob]      = s_tot;
        partial[bg * 128 + 64 + o_glob] = q_tot;
    }
}

// ---------------------------------------------------------------------------
// Pass 2: reduce partials -> per-channel mean and rsqrt(var+eps)
// ---------------------------------------------------------------------------
__global__ __launch_bounds__(256) void gcn_stats(
    const float* __restrict__ partial, float* __restrict__ stats)
{
    const int o = blockIdx.x;      // 64 blocks, one per channel
    const int tid = threadIdx.x;
    float s = 0.f, q = 0.f;
    for (int blk = tid; blk < NBLK1; blk += 256) {
        s += partial[blk * 128 + o];
        q += partial[blk * 128 + 64 + o];
    }
    __shared__ float rs[256], rq[256];
    rs[tid] = s; rq[tid] = q;
    __syncthreads();
    for (int off = 128; off > 0; off >>= 1) {
        if (tid < off) { rs[tid] += rs[tid + off]; rq[tid] += rq[tid + off]; }
        __syncthreads();
    }
    if (tid == 0) {
        float mean = rs[0] / (float)NTV;
        float var  = rq[0] / (float)NTV - mean * mean;   // biased, like jnp.var
        stats[o]      = mean;
        stats[64 + o] = rsqrtf(var + BN_EPS);
    }
}

// ---------------------------------------------------------------------------
// Pass 3: un-scatter via LDS + BN + residual + ReLU, fully coalesced float4.
// One block per 8-t group: int4-copy its 8 tiles (28,672 B) into LDS, then
// stream 64 o-runs x 200 floats as float4 (x read / out write coalesced).
// ---------------------------------------------------------------------------
__global__ __launch_bounds__(256) void gcn_finalize_b(
    const float* __restrict__ x, const float* __restrict__ gamma,
    const float* __restrict__ beta, const float* __restrict__ stats,
    const short* __restrict__ scr, float* __restrict__ out)
{
    __shared__ __align__(16) short tl_s[8 * TILE_SH];   // 28,672 B
    const int bid  = blockIdx.x;           // 0..2047
    const int n    = bid >> 6;
    const int tgrp = bid & 63;
    const int tid  = threadIdx.x;

    const int4* src = (const int4*)(scr + (size_t)bid * 8 * TILE_SH);
    int4* dst4 = (int4*)tl_s;
    #pragma unroll
    for (int k = 0; k < 7; ++k) dst4[tid + k * 256] = src[tid + k * 256]; // 1792
    __syncthreads();

    const size_t obase = (size_t)n * 819200 + (size_t)tgrp * 200;
    #pragma unroll
    for (int k = 0; k < 13; ++k) {
        int fi = tid + k * 256;
        if (fi < 3200) {
            int o  = fi / 50;                 // 50 float4 per o-run
            int p  = (fi - o * 50) * 4;       // 0..196
            int tl = p / 25;
            int v0 = p - tl * 25;
            float gm = gamma[o] * stats[64 + o];
            float bc = beta[o] - gm * stats[o];
            size_t gidx = obase + (size_t)o * 12800 + p;
            float4 xv = *(const float4*)(x + gidx);
            float r[4];
            #pragma unroll
            for (int j = 0; j < 4; ++j) {
                int vv = v0 + j, tt = tl;
                if (vv >= 25) { vv -= 25; tt += 1; }
                int off = (vv < 16)
                    ? ((o >> 4) * 256 + (vv >> 2) * 64 + (o & 15) * 4 + (vv & 3))
                    : (1024 + (o >> 4) * 192 + ((vv - 16) >> 2) * 64
                       + (o & 15) * 4 + (vv & 3));
                float pv = bf2f(tl_s[tt * TILE_SH + off]);
                r[j] = fmaxf(fmaf(gm, pv, bc) + (&xv.x)[j], 0.f);
            }
            float4 o4; o4.x = r[0]; o4.y = r[1]; o4.z = r[2]; o4.w = r[3];
            *(float4*)(out + gidx) = o4;
        }
    }
}

// ---------------------------------------------------------------------------
// Pass 3 (fallback, fp32 scratch == out): in-place elementwise
// ---------------------------------------------------------------------------
__global__ __launch_bounds__(256) void gcn_finalize_f(
    const float* __restrict__ x, const float* __restrict__ gamma,
    const float* __restrict__ beta, const float* __restrict__ stats,
    float* __restrict__ out)
{
    const int total4 = NTOT / 4;
    for (int i = blockIdx.x * blockDim.x + threadIdx.x; i < total4;
         i += gridDim.x * blockDim.x) {
        int chan = ((i * 4) / (T_DIM * V_DIM)) & 63;
        float4 p  = ((const float4*)out)[i];
        float4 xv = ((const float4*)x)[i];
        float m = stats[chan], r = stats[64 + chan];
        float g = gamma[chan] * r;
        float bc = beta[chan] - g * m;
        p.x = fmaxf(fmaf(g, p.x, bc) + xv.x, 0.f);
        p.y = fmaxf(fmaf(g, p.y, bc) + xv.y, 0.f);
        p.z = fmaxf(fmaf(g, p.z, bc) + xv.z, 0.f);
        p.w = fmaxf(fmaf(g, p.w, bc) + xv.w, 0.f);
        ((float4*)out)[i] = p;
    }
}

extern "C" void kernel_launch(void* const* d_in, const int* in_sizes, int n_in,
                              void* d_out, int out_size, void* d_ws, size_t ws_size,
                              hipStream_t stream) {
    const float* x     = (const float*)d_in[0];
    const float* A     = (const float*)d_in[1];
    const float* W     = (const float*)d_in[2];
    // d_in[3] = b : unused — per-channel bias cancels exactly through BatchNorm
    const float* gamma = (const float*)d_in[4];
    const float* beta  = (const float*)d_in[5];
    float* out = (float*)d_out;

    const size_t scr_bytes   = (size_t)N_DIM * T_DIM * TILE_SH * 2;  // 58,720,256
    const size_t part_bytes  = (size_t)NBLK1 * 128 * 4;              // 262,144
    const size_t stats_bytes = 512;
    const size_t pack_bytes  = 2 * 6 * 256 * 8 * 2;                  // 49,152

    if (ws_size >= scr_bytes + part_bytes + stats_bytes + pack_bytes) {
        short* scr     = (short*)d_ws;
        float* partial = (float*)((char*)d_ws + scr_bytes);
        float* stats   = partial + NBLK1 * 128;
        short* wpack   = (short*)((char*)d_ws + scr_bytes + part_bytes + stats_bytes);
        short* apack   = wpack + 6 * 256 * 8;

        gcn_pack<<<12, 256, 0, stream>>>(A, W, wpack, apack);
        gcn_pass1<1><<<NBLK1, 256, 0, stream>>>(x, A, W, wpack, apack,
                                                (void*)scr, partial);
        gcn_stats<<<64, 256, 0, stream>>>(partial, stats);
        gcn_finalize_b<<<NTGRP, 256, 0, stream>>>(x, gamma, beta, stats, scr, out);
    } else {
        float* partial = (float*)d_ws;
        float* stats   = partial + NBLK1 * 128;
        gcn_pass1<0><<<NBLK1, 256, 0, stream>>>(x, A, W, nullptr, nullptr,
                                                (void*)out, partial);
        gcn_stats<<<64, 256, 0, stream>>>(partial, stats);
        gcn_finalize_f<<<2048, 256, 0, stream>>>(x, gamma, beta, stats, out);
    }
}